// Round 2
// baseline (170.553 us; speedup 1.0000x reference)
//
#include <hip/hip_runtime.h>

// PooledMSELoss: mean((box9(pred) - box9(target))^2) = mean(box9(pred-tgt)^2)
// B,C,T,H,W = 4,2,8,512,512 fp32; POOL=9, zero pad on H,W, /81 per smooth.
//
// One block = one 8-row output chunk of one 512x512 image.
// Loads all 16 contributing input rows with batched, branchless (clamped)
// float2 loads -> MLP ~32/thread (R1 was latency-bound at MLP 2).

constexpr int Hh    = 512;
constexpr int Ww    = 512;
constexpr int PAD   = 4;            // POOL/2
constexpr int CHUNK = 8;            // output rows per block
constexpr int LROW  = Ww + 2 * PAD; // 520 floats per LDS row

__global__ __launch_bounds__(256, 4)
void pooled_mse_kernel(const float* __restrict__ pred,
                       const float* __restrict__ tgt,
                       float* __restrict__ out) {
    __shared__ float lds[CHUNK][LROW];

    const int tid = threadIdx.x;
    const int img = blockIdx.x >> 6;            // 64 strips per image
    const int sy  = (blockIdx.x & 63) * CHUNK;  // first output row

    const size_t ibase = (size_t)img * Hh * Ww;
    const float2* p2 = (const float2*)(pred + ibase);
    const float2* t2 = (const float2*)(tgt + ibase);

    // Zero the horizontal halos (never overwritten afterwards).
    if (tid < CHUNK) {
        #pragma unroll
        for (int k = 0; k < PAD; ++k) {
            lds[tid][k] = 0.0f;
            lds[tid][PAD + Ww + k] = 0.0f;
        }
    }

    // Vertical 9-sum accumulators for the 8 output rows.
    float2 v[CHUNK];
    #pragma unroll
    for (int k = 0; k < CHUNK; ++k) v[k] = make_float2(0.0f, 0.0f);

    // 16 input rows (sy-4 .. sy+11) in two batches of 8 rows.
    // Loads are branchless (clamped row + zero mask) so all 16 loads of a
    // batch issue back-to-back before any waitcnt.
    #pragma unroll
    for (int g = 0; g < 2; ++g) {
        float2 pa[8], tb[8];
        float  mk[8];
        #pragma unroll
        for (int r = 0; r < 8; ++r) {
            int y = sy - PAD + g * 8 + r;
            bool valid = (unsigned)y < (unsigned)Hh;
            int yc = valid ? y : 0;
            mk[r] = valid ? 1.0f : 0.0f;
            pa[r] = p2[(size_t)yc * (Ww / 2) + tid];
            tb[r] = t2[(size_t)yc * (Ww / 2) + tid];
        }
        #pragma unroll
        for (int r = 0; r < 8; ++r) {
            const int ri = g * 8 + r;   // input row index 0..15 (= y-(sy-4))
            float dx = (pa[r].x - tb[r].x) * mk[r];
            float dy = (pa[r].y - tb[r].y) * mk[r];
            // input row ri feeds output rows k with k <= ri <= k+8
            #pragma unroll
            for (int k = 0; k < CHUNK; ++k) {
                if (ri >= k && ri <= k + 8) { v[k].x += dx; v[k].y += dy; }
            }
        }
    }

    // Vertical sums -> LDS rows.
    #pragma unroll
    for (int k = 0; k < CHUNK; ++k) {
        lds[k][PAD + 2 * tid]     = v[k].x;
        lds[k][PAD + 2 * tid + 1] = v[k].y;
    }
    __syncthreads();

    // Horizontal 9-sums + accumulate squares.
    float acc = 0.0f;
    #pragma unroll
    for (int r = 0; r < CHUNK; ++r) {
        float s[10];
        #pragma unroll
        for (int k = 0; k < 10; ++k) s[k] = lds[r][2 * tid + k];
        float t8 = s[1];
        #pragma unroll
        for (int k = 2; k <= 8; ++k) t8 += s[k];
        float o0 = t8 + s[0];   // column 2*tid
        float o1 = t8 + s[9];   // column 2*tid+1
        acc = fmaf(o0, o0, acc);
        acc = fmaf(o1, o1, acc);
    }

    // Wave shuffle reduce, cross-wave via LDS, one atomic per block.
    #pragma unroll
    for (int off = 32; off > 0; off >>= 1)
        acc += __shfl_down(acc, off, 64);

    __shared__ float wsum[4];
    const int wid = tid >> 6, lane = tid & 63;
    if (lane == 0) wsum[wid] = acc;
    __syncthreads();
    if (tid == 0) {
        float b = wsum[0] + wsum[1] + wsum[2] + wsum[3];
        const float scale = 1.0f / (81.0f * 81.0f * 16777216.0f);
        atomicAdd(out, b * scale);
    }
}

extern "C" void kernel_launch(void* const* d_in, const int* in_sizes, int n_in,
                              void* d_out, int out_size, void* d_ws, size_t ws_size,
                              hipStream_t stream) {
    const float* pred = (const float*)d_in[0];
    const float* tgt  = (const float*)d_in[1];
    float* out = (float*)d_out;

    // d_out is re-poisoned to 0xAA before every timed launch.
    hipMemsetAsync(out, 0, sizeof(float), stream);

    const int nblocks = 64 * 64;   // 64 images * 64 eight-row strips
    pooled_mse_kernel<<<nblocks, 256, 0, stream>>>(pred, tgt, out);
}

// Round 3
// 149.892 us; speedup vs baseline: 1.1378x; 1.1378x over previous
//
#include <hip/hip_runtime.h>

// PooledMSELoss: mean((box9(pred) - box9(target))^2) = mean(box9(pred-tgt)^2)
// B,C,T,H,W = 4,2,8,512,512 fp32; POOL=9, zero pad on H,W, /81 per smooth.
//
// R3: 64-row strips, 8-row chunks, register double-buffered distance-1
// prefetch of 16-load windows, pinned with sched_barrier(0) so the compiler
// cannot sink loads into the consume loop (R2 failure mode: VGPR=32 proved
// loads were serialized, block time == 32 load latencies).

constexpr int Hh    = 512;
constexpr int Ww    = 512;
constexpr int PAD   = 4;            // POOL/2
constexpr int ROWS  = 64;           // output rows per block
constexpr int CHUNK = 8;            // rows per chunk
constexpr int LROW  = Ww + 2 * PAD; // 520 floats per LDS row

__global__ __launch_bounds__(256, 2)
void pooled_mse_kernel(const float* __restrict__ pred,
                       const float* __restrict__ tgt,
                       float* __restrict__ out) {
    __shared__ float lds[CHUNK][LROW];
    __shared__ float wsum[4];

    const int tid = threadIdx.x;
    const int img = blockIdx.x >> 3;            // 8 strips per image
    const int sy  = (blockIdx.x & 7) * ROWS;    // first output row of strip

    const size_t ibase = (size_t)img * Hh * Ww;
    const float2* p2 = (const float2*)(pred + ibase);
    const float2* t2 = (const float2*)(tgt + ibase);

    // Zero the horizontal halos once (never overwritten afterwards).
    if (tid < CHUNK) {
        #pragma unroll
        for (int k = 0; k < PAD; ++k) {
            lds[tid][k] = 0.0f;
            lds[tid][PAD + Ww + k] = 0.0f;
        }
    }

    // Window W(j), j=0..8: input rows sy+8j-4 .. sy+8j+3.
    // Chunk c consumes W(c) (w[0..7]) and W(c+1) (w[8..15]).
    float2 rawP[2][8], rawT[2][8];   // raw load double-buffer
    float2 d[2][8];                  // masked differences

    auto issue = [&](int j, int b) {   // j,b compile-time under full unroll
        #pragma unroll
        for (int r = 0; r < 8; ++r) {
            int y  = sy + 8 * j - PAD + r;
            int yc = y < 0 ? 0 : (y > Hh - 1 ? Hh - 1 : y);   // clamped addr
            size_t off = (size_t)yc * (Ww / 2) + tid;
            rawP[b][r] = p2[off];
            rawT[b][r] = t2[off];
        }
        // Pin: all 16 loads of this window issue before anything below.
        __builtin_amdgcn_sched_barrier(0);
    };
    auto diffw = [&](int j, int b) {
        #pragma unroll
        for (int r = 0; r < 8; ++r) {
            int y = sy + 8 * j - PAD + r;
            float mk = ((unsigned)y < (unsigned)Hh) ? 1.0f : 0.0f; // zero pad
            d[b][r].x = (rawP[b][r].x - rawT[b][r].x) * mk;
            d[b][r].y = (rawP[b][r].y - rawT[b][r].y) * mk;
        }
    };

    // Prologue: two windows in flight before first consume.
    issue(0, 0);
    issue(1, 1);
    diffw(0, 0);

    float acc = 0.0f;

    #pragma unroll
    for (int c = 0; c < 8; ++c) {
        if (c < 7) issue(c + 2, c & 1);   // prefetch next-next window
        diffw(c + 1, (c + 1) & 1);        // waits on W(c+1), W(c+2) still flying

        // Vertical 9-sums for the 8 output rows of this chunk -> LDS.
        // Output row k needs w[k..k+8]; incremental sliding sum.
        {
            const int bA = c & 1, bB = (c + 1) & 1;
            float sx = d[bA][0].x, sv = d[bA][0].y;
            #pragma unroll
            for (int i = 1; i < 8; ++i) { sx += d[bA][i].x; sv += d[bA][i].y; }
            sx += d[bB][0].x; sv += d[bB][0].y;
            lds[0][PAD + 2 * tid]     = sx;
            lds[0][PAD + 2 * tid + 1] = sv;
            #pragma unroll
            for (int k = 1; k < 8; ++k) {
                sx += d[bB][k].x - d[bA][k - 1].x;
                sv += d[bB][k].y - d[bA][k - 1].y;
                lds[k][PAD + 2 * tid]     = sx;
                lds[k][PAD + 2 * tid + 1] = sv;
            }
        }
        __syncthreads();

        // Horizontal 9-sums + accumulate squares.
        #pragma unroll
        for (int r = 0; r < CHUNK; ++r) {
            float s[10];
            #pragma unroll
            for (int k = 0; k < 10; ++k) s[k] = lds[r][2 * tid + k];
            float t8 = s[1];
            #pragma unroll
            for (int k = 2; k <= 8; ++k) t8 += s[k];
            float o0 = t8 + s[0];
            float o1 = t8 + s[9];
            acc = fmaf(o0, o0, acc);
            acc = fmaf(o1, o1, acc);
        }
        __syncthreads();   // before next chunk overwrites LDS
    }

    // Wave shuffle reduce, cross-wave via LDS, one atomic per block.
    #pragma unroll
    for (int off = 32; off > 0; off >>= 1)
        acc += __shfl_down(acc, off, 64);

    const int wid = tid >> 6, lane = tid & 63;
    if (lane == 0) wsum[wid] = acc;
    __syncthreads();
    if (tid == 0) {
        float b = wsum[0] + wsum[1] + wsum[2] + wsum[3];
        const float scale = 1.0f / (81.0f * 81.0f * 16777216.0f);
        atomicAdd(out, b * scale);
    }
}

extern "C" void kernel_launch(void* const* d_in, const int* in_sizes, int n_in,
                              void* d_out, int out_size, void* d_ws, size_t ws_size,
                              hipStream_t stream) {
    const float* pred = (const float*)d_in[0];
    const float* tgt  = (const float*)d_in[1];
    float* out = (float*)d_out;

    // d_out is re-poisoned to 0xAA before every timed launch.
    hipMemsetAsync(out, 0, sizeof(float), stream);

    const int nblocks = 64 * (Hh / ROWS);   // 64 images * 8 strips = 512
    pooled_mse_kernel<<<nblocks, 256, 0, stream>>>(pred, tgt, out);
}